// Round 2
// baseline (733.820 us; speedup 1.0000x reference)
//
#include <hip/hip_runtime.h>

#define BATCH 16384
#define KDIM  3072
#define NDIM  3072

typedef __bf16 bf16;
typedef bf16  bf16x8  __attribute__((ext_vector_type(8)));
typedef float f32x16  __attribute__((ext_vector_type(16)));

// async global->LDS, 16B per lane. HW dest = wave-uniform base + lane*16,
// which our lds addressing (tid*16B) satisfies.
__device__ __forceinline__ void g2l16(const bf16* g, bf16* l) {
    __builtin_amdgcn_global_load_lds(
        (__attribute__((address_space(1))) unsigned int*)g,
        (__attribute__((address_space(3))) unsigned int*)l,
        16, 0, 0);
}

// ---- prep 1: fp32 inputs -> bf16, 8 elems/thread ----
__global__ __launch_bounds__(256) void cvt_a_kernel(const float* __restrict__ in,
                                                    bf16* __restrict__ out) {
    const long idx = (long)blockIdx.x * 256 + threadIdx.x;
    const float4* in4 = (const float4*)in;
    float4 a = in4[idx * 2];
    float4 b = in4[idx * 2 + 1];
    bf16x8 o;
    o[0] = (bf16)a.x; o[1] = (bf16)a.y; o[2] = (bf16)a.z; o[3] = (bf16)a.w;
    o[4] = (bf16)b.x; o[5] = (bf16)b.y; o[6] = (bf16)b.z; o[7] = (bf16)b.w;
    ((bf16x8*)out)[idx] = o;
}

// ---- prep 2: Weff_t[u][i] = bf16(w[i][u] * mask[u][i]) via LDS transpose ----
__global__ __launch_bounds__(256) void weff_kernel(const float* __restrict__ w,
                                                   const int* __restrict__ mask,
                                                   bf16* __restrict__ wt) {
    __shared__ float tile[32][33];  // +1 pad: no bank conflicts on transpose read
    const int i0 = blockIdx.x * 32;
    const int u0 = blockIdx.y * 32;
    const int tx = threadIdx.x, ty = threadIdx.y;
#pragma unroll
    for (int r = 0; r < 4; r++)
        tile[ty + 8 * r][tx] = w[(long)(i0 + ty + 8 * r) * NDIM + u0 + tx];
    __syncthreads();
#pragma unroll
    for (int r = 0; r < 4; r++) {
        int u = u0 + ty + 8 * r;
        int i = i0 + tx;
        float v = tile[tx][ty + 8 * r] * (float)mask[(long)u * KDIM + i];
        wt[(long)u * KDIM + i] = (bf16)v;
    }
}

// ---- main GEMM: C[m][n] = A[m][k] * Bt[n][k] + bias[n] ----
// 128x128 tile, BK=32, 4 waves in 2x2, each wave 64x64 via 2x2 mfma 32x32x16.
// LDS tiles use an XOR chunk swizzle: within a 64B row (4 chunks of 16B),
// slot s holds global chunk c = s ^ ((row>>1)&3). This makes every 16-lane
// ds_read_b128 phase hit each bank-granule exactly twice (2-way = free).
__global__ __launch_bounds__(256) void gemm_kernel(const bf16* __restrict__ A,   // [BATCH][KDIM]
                                                   const bf16* __restrict__ Bt,  // [NDIM][KDIM]
                                                   const float* __restrict__ bias,
                                                   float* __restrict__ C) {      // [BATCH][NDIM]
    __shared__ __align__(16) bf16 lds[8192];  // A tile 128x32 @0, B tile 128x32 @4096

    const int tid  = threadIdx.x;
    const int lane = tid & 63;
    const int wv   = tid >> 6;
    const long m0 = (long)blockIdx.y * 128;
    const long n0 = (long)blockIdx.x * 128;
    const int waveM = (wv >> 1) * 64;
    const int waveN = (wv & 1) * 64;

    // staging: lane tid writes LDS bytes [tid*16, tid*16+16) -> row=tid>>2,
    // slot=tid&3. Fetch the swizzled global chunk for that slot.
    const int srow   = tid >> 2;
    const int schunk = (tid & 3) ^ ((tid >> 3) & 3);
    const bf16* gA = A + (m0 + srow) * KDIM + schunk * 8;
    const bf16* gB = Bt + (n0 + srow) * KDIM + schunk * 8;
    bf16* lA = &lds[tid * 8];
    bf16* lB = &lds[4096 + tid * 8];

    // fragment read addressing (A[m][k], B[n][k], k-contiguous, swizzled):
    // for subtile x and k-step t: elem = (waveX + x*32 + rl)*32 + ((2t+kb)^rsw)*8
    const int rl  = lane & 31;
    const int kb  = lane >> 5;        // k-half of the wave
    const int rsw = (rl >> 1) & 3;    // row swizzle key
    const bf16* fA0 = &lds[(waveM + rl) * 32];
    const bf16* fB0 = &lds[4096 + (waveN + rl) * 32];
    const int c0 = ((0 + kb) ^ rsw) * 8;  // k-step 0 chunk offset (elems)
    const int c1 = ((2 + kb) ^ rsw) * 8;  // k-step 1 chunk offset (elems)

    f32x16 acc[2][2] = {};

    for (int k0 = 0; k0 < KDIM; k0 += 32) {
        __syncthreads();  // LDS consumed by previous iter's MFMAs
        g2l16(gA, lA);
        g2l16(gA + 64 * KDIM, lA + 2048);
        g2l16(gB, lB);
        g2l16(gB + 64 * KDIM, lB + 2048);
        gA += 32;
        gB += 32;
        __syncthreads();  // staging complete (compiler drains vmcnt)

        bf16x8 a0[2], a1[2], b0[2], b1[2];
#pragma unroll
        for (int mi = 0; mi < 2; mi++) {
            a0[mi] = *(const bf16x8*)(fA0 + mi * 1024 + c0);
            a1[mi] = *(const bf16x8*)(fA0 + mi * 1024 + c1);
        }
#pragma unroll
        for (int ni = 0; ni < 2; ni++) {
            b0[ni] = *(const bf16x8*)(fB0 + ni * 1024 + c0);
            b1[ni] = *(const bf16x8*)(fB0 + ni * 1024 + c1);
        }
#pragma unroll
        for (int mi = 0; mi < 2; mi++)
#pragma unroll
            for (int ni = 0; ni < 2; ni++) {
                acc[mi][ni] = __builtin_amdgcn_mfma_f32_32x32x16_bf16(
                    a0[mi], b0[ni], acc[mi][ni], 0, 0, 0);
                acc[mi][ni] = __builtin_amdgcn_mfma_f32_32x32x16_bf16(
                    a1[mi], b1[ni], acc[mi][ni], 0, 0, 0);
            }
    }

    // epilogue: C/D layout col=lane&31, row=(reg&3)+8*(reg>>2)+4*(lane>>5)
#pragma unroll
    for (int mi = 0; mi < 2; mi++) {
#pragma unroll
        for (int ni = 0; ni < 2; ni++) {
            const long col  = n0 + waveN + ni * 32 + rl;
            const long rbase = m0 + waveM + mi * 32 + 4 * kb;
            const float bv = bias[col];
#pragma unroll
            for (int g = 0; g < 4; g++)
#pragma unroll
                for (int t = 0; t < 4; t++)
                    C[(rbase + 8 * g + t) * NDIM + col] = acc[mi][ni][4 * g + t] + bv;
        }
    }
}

// ---- fallback (only if ws_size too small): naive fp32 masked GEMM ----
__global__ __launch_bounds__(256) void naive_kernel(const float* __restrict__ x,
                                                    const float* __restrict__ w,
                                                    const float* __restrict__ bias,
                                                    const int* __restrict__ mask,
                                                    float* __restrict__ out) {
    const long idx = (long)blockIdx.x * 256 + threadIdx.x;
    const long bi = idx / NDIM;
    const int u = (int)(idx % NDIM);
    float s = 0.f;
    for (int k = 0; k < KDIM; k++)
        s += x[bi * KDIM + k] * w[(long)k * NDIM + u] * (float)mask[(long)u * KDIM + k];
    out[idx] = s + bias[u];
}

extern "C" void kernel_launch(void* const* d_in, const int* in_sizes, int n_in,
                              void* d_out, int out_size, void* d_ws, size_t ws_size,
                              hipStream_t stream) {
    const float* x    = (const float*)d_in[0];  // [16384, 3072] fp32
    const float* w    = (const float*)d_in[1];  // [3072, 3072] fp32
    const float* bias = (const float*)d_in[2];  // [3072] fp32
    const int*   mask = (const int*)d_in[3];    // [3072, 3072] int32
    float* out = (float*)d_out;                 // [16384, 3072] fp32

    const size_t needA = (size_t)BATCH * KDIM * sizeof(bf16);  // ~100.7 MB
    const size_t needW = (size_t)NDIM * KDIM * sizeof(bf16);   // ~18.9 MB

    if (ws_size < needA + needW) {
        const long total = (long)BATCH * NDIM;
        naive_kernel<<<(int)(total / 256), 256, 0, stream>>>(x, w, bias, mask, out);
        return;
    }

    bf16* Abf = (bf16*)d_ws;
    bf16* Wt  = (bf16*)((char*)d_ws + needA);

    cvt_a_kernel<<<(BATCH * (KDIM / 8)) / 256, 256, 0, stream>>>(x, Abf);
    weff_kernel<<<dim3(KDIM / 32, NDIM / 32), dim3(32, 8), 0, stream>>>(w, mask, Wt);
    gemm_kernel<<<dim3(NDIM / 128, BATCH / 128), 256, 0, stream>>>(Abf, Wt, bias, out);
}

// Round 3
// 691.260 us; speedup vs baseline: 1.0616x; 1.0616x over previous
//
#include <hip/hip_runtime.h>

#define BATCH 16384
#define KDIM  3072
#define NDIM  3072

typedef __bf16 bf16;
typedef bf16  bf16x8  __attribute__((ext_vector_type(8)));
typedef float f32x16  __attribute__((ext_vector_type(16)));

// async global->LDS, 16B per lane. HW dest = wave-uniform base + lane*16,
// which our lds addressing (tid*16B within each 4KB call) satisfies.
__device__ __forceinline__ void g2l16(const bf16* g, bf16* l) {
    __builtin_amdgcn_global_load_lds(
        (__attribute__((address_space(1))) unsigned int*)g,
        (__attribute__((address_space(3))) unsigned int*)l,
        16, 0, 0);
}

// ---- prep 1: fp32 inputs -> bf16, 8 elems/thread ----
__global__ __launch_bounds__(256) void cvt_a_kernel(const float* __restrict__ in,
                                                    bf16* __restrict__ out) {
    const long idx = (long)blockIdx.x * 256 + threadIdx.x;
    const float4* in4 = (const float4*)in;
    float4 a = in4[idx * 2];
    float4 b = in4[idx * 2 + 1];
    bf16x8 o;
    o[0] = (bf16)a.x; o[1] = (bf16)a.y; o[2] = (bf16)a.z; o[3] = (bf16)a.w;
    o[4] = (bf16)b.x; o[5] = (bf16)b.y; o[6] = (bf16)b.z; o[7] = (bf16)b.w;
    ((bf16x8*)out)[idx] = o;
}

// ---- prep 2: Weff_t[u][i] = bf16(w[i][u] * mask[u][i]) via LDS transpose ----
__global__ __launch_bounds__(256) void weff_kernel(const float* __restrict__ w,
                                                   const int* __restrict__ mask,
                                                   bf16* __restrict__ wt) {
    __shared__ float tile[32][33];
    const int i0 = blockIdx.x * 32;
    const int u0 = blockIdx.y * 32;
    const int tx = threadIdx.x, ty = threadIdx.y;
#pragma unroll
    for (int r = 0; r < 4; r++)
        tile[ty + 8 * r][tx] = w[(long)(i0 + ty + 8 * r) * NDIM + u0 + tx];
    __syncthreads();
#pragma unroll
    for (int r = 0; r < 4; r++) {
        int u = u0 + ty + 8 * r;
        int i = i0 + tx;
        float v = tile[tx][ty + 8 * r] * (float)mask[(long)u * KDIM + i];
        wt[(long)u * KDIM + i] = (bf16)v;
    }
}

// ---- main GEMM: C[m][n] = A[m][k] * Bt[n][k] + bias[n] ----
// Block tile 256x128, BK=32. 4 waves in 2x2; each wave 128x64 via 4x2 grid of
// mfma_f32_32x32x16. Double-buffered LDS: DMA for tile i+1 issued BEFORE the
// ds_reads/MFMAs of tile i, so the compiler's vmcnt(0)-before-barrier lands
// after ~500+ cycles of overlap. One __syncthreads per K-iter.
// LDS per buffer: A 256x32 bf16 (16KB, elems 0..8191) + B 128x32 (8KB,
// elems 8192..12287). Two buffers = 48KB.
__global__ __launch_bounds__(256, 2) void gemm_kernel(const bf16* __restrict__ A,   // [BATCH][KDIM]
                                                      const bf16* __restrict__ Bt,  // [NDIM][KDIM]
                                                      const float* __restrict__ bias,
                                                      float* __restrict__ C) {      // [BATCH][NDIM]
    __shared__ __align__(16) bf16 lds[2 * 12288];

    const int tid  = threadIdx.x;
    const int lane = tid & 63;
    const int wv   = tid >> 6;
    const long m0 = (long)blockIdx.y * 256;
    const long n0 = (long)blockIdx.x * 128;
    const int waveM = (wv >> 1) * 128;
    const int waveN = (wv & 1) * 64;

    // staging: call j stages rows 64j..64j+63 (row = 64j + tid>>2, chunk tid&3)
    const int srow   = tid >> 2;
    const int schunk = tid & 3;
    const bf16* gA = A + (m0 + srow) * KDIM + schunk * 8;
    const bf16* gB = Bt + (n0 + srow) * KDIM + schunk * 8;

    // fragment addressing: row-major [row][32k] per region, chunk c = 2t+kb
    const int rl = lane & 31;
    const int kb = lane >> 5;
    const int aBase = (waveM + rl) * 32 + kb * 8;
    const int bBase = 8192 + (waveN + rl) * 32 + kb * 8;

    f32x16 acc[4][2] = {};

    // prologue: stage tile 0 into buf 0
    {
        bf16* d = &lds[tid * 8];
#pragma unroll
        for (int j = 0; j < 4; j++) g2l16(gA + (long)(64 * j) * KDIM, d + j * 2048);
#pragma unroll
        for (int j = 0; j < 2; j++) g2l16(gB + (long)(64 * j) * KDIM, d + 8192 + j * 2048);
    }
    __syncthreads();

    for (int i = 0; i < KDIM / 32; ++i) {
        const int p = i & 1;
        // issue DMA for tile i+1 into the other buffer (in flight during MFMAs)
        if (i + 1 < KDIM / 32) {
            const long ko = (long)(i + 1) * 32;
            bf16* d = &lds[(1 - p) * 12288 + tid * 8];
#pragma unroll
            for (int j = 0; j < 4; j++) g2l16(gA + (long)(64 * j) * KDIM + ko, d + j * 2048);
#pragma unroll
            for (int j = 0; j < 2; j++) g2l16(gB + (long)(64 * j) * KDIM + ko, d + 8192 + j * 2048);
        }

        const bf16* bp = &lds[p * 12288];
#pragma unroll
        for (int t = 0; t < 2; t++) {
            bf16x8 a[4], b[2];
#pragma unroll
            for (int mi = 0; mi < 4; mi++)
                a[mi] = *(const bf16x8*)(bp + aBase + mi * 1024 + t * 16);
#pragma unroll
            for (int ni = 0; ni < 2; ni++)
                b[ni] = *(const bf16x8*)(bp + bBase + ni * 1024 + t * 16);
#pragma unroll
            for (int mi = 0; mi < 4; mi++)
#pragma unroll
                for (int ni = 0; ni < 2; ni++)
                    acc[mi][ni] = __builtin_amdgcn_mfma_f32_32x32x16_bf16(
                        a[mi], b[ni], acc[mi][ni], 0, 0, 0);
        }
        __syncthreads();  // drains vmcnt(0): DMA latency already overlapped
    }

    // epilogue: C/D layout col=lane&31, row=(reg&3)+8*(reg>>2)+4*(lane>>5)
#pragma unroll
    for (int mi = 0; mi < 4; mi++) {
#pragma unroll
        for (int ni = 0; ni < 2; ni++) {
            const long col   = n0 + waveN + ni * 32 + rl;
            const long rbase = m0 + waveM + mi * 32 + 4 * kb;
            const float bv = bias[col];
#pragma unroll
            for (int g = 0; g < 4; g++)
#pragma unroll
                for (int t = 0; t < 4; t++)
                    C[(rbase + 8 * g + t) * NDIM + col] = acc[mi][ni][4 * g + t] + bv;
        }
    }
}

// ---- fallback (only if ws_size too small): naive fp32 masked GEMM ----
__global__ __launch_bounds__(256) void naive_kernel(const float* __restrict__ x,
                                                    const float* __restrict__ w,
                                                    const float* __restrict__ bias,
                                                    const int* __restrict__ mask,
                                                    float* __restrict__ out) {
    const long idx = (long)blockIdx.x * 256 + threadIdx.x;
    const long bi = idx / NDIM;
    const int u = (int)(idx % NDIM);
    float s = 0.f;
    for (int k = 0; k < KDIM; k++)
        s += x[bi * KDIM + k] * w[(long)k * NDIM + u] * (float)mask[(long)u * KDIM + k];
    out[idx] = s + bias[u];
}

extern "C" void kernel_launch(void* const* d_in, const int* in_sizes, int n_in,
                              void* d_out, int out_size, void* d_ws, size_t ws_size,
                              hipStream_t stream) {
    const float* x    = (const float*)d_in[0];  // [16384, 3072] fp32
    const float* w    = (const float*)d_in[1];  // [3072, 3072] fp32
    const float* bias = (const float*)d_in[2];  // [3072] fp32
    const int*   mask = (const int*)d_in[3];    // [3072, 3072] int32
    float* out = (float*)d_out;                 // [16384, 3072] fp32

    const size_t needA = (size_t)BATCH * KDIM * sizeof(bf16);  // ~100.7 MB
    const size_t needW = (size_t)NDIM * KDIM * sizeof(bf16);   // ~18.9 MB

    if (ws_size < needA + needW) {
        const long total = (long)BATCH * NDIM;
        naive_kernel<<<(int)(total / 256), 256, 0, stream>>>(x, w, bias, mask, out);
        return;
    }

    bf16* Abf = (bf16*)d_ws;
    bf16* Wt  = (bf16*)((char*)d_ws + needA);

    cvt_a_kernel<<<(BATCH * (KDIM / 8)) / 256, 256, 0, stream>>>(x, Abf);
    weff_kernel<<<dim3(KDIM / 32, NDIM / 32), dim3(32, 8), 0, stream>>>(w, mask, Wt);
    gemm_kernel<<<dim3(NDIM / 128, BATCH / 256), 256, 0, stream>>>(Abf, Wt, bias, out);
}